// Round 2
// baseline (6559.921 us; speedup 1.0000x reference)
//
#include <hip/hip_runtime.h>
#include <hip/hip_bf16.h>
#include <math.h>

#define H    1024
#define NST  64
#define LAYN 2
#define BSZ  32
#define TLEN 512
#define NSTEPS 16
#define H2   2048

__device__ __forceinline__ float gelu_f(float x){
    return 0.5f*x*(1.0f+erff(x*0.7071067811865475f));
}
__device__ __forceinline__ float sigm_f(float x){
    return 1.0f/(1.0f+expf(-x));
}

// ---------------- discretized SSM params: dA = exp(dt*A), dB = (dA-1)/A * B ----------------
__global__ void k_precompute(const float* __restrict__ log_dt,
                             const float* __restrict__ Are, const float* __restrict__ Aim,
                             const float* __restrict__ Bre, const float* __restrict__ Bim,
                             float* __restrict__ dAr, float* __restrict__ dAi,
                             float* __restrict__ dBr, float* __restrict__ dBi){
    int i = blockIdx.x*256 + threadIdx.x;
    if (i >= LAYN*H*NST) return;
    int lh = i / NST;
    float dt = expf(log_dt[lh]);
    float ar = Are[i], ai = Aim[i];
    float e  = expf(dt*ar);
    float sa, ca; sincosf(dt*ai, &sa, &ca);
    float dar = e*ca, dai = e*sa;
    float zr = dar-1.0f, zi = dai;
    float inv = 1.0f/(ar*ar + ai*ai);
    float wr = (zr*ar + zi*ai)*inv;
    float wi = (zi*ar - zr*ai)*inv;
    float br = Bre[i], bi = Bim[i];
    dAr[i]=dar; dAi[i]=dai;
    dBr[i]=wr*br - wi*bi;
    dBi[i]=wr*bi + wi*br;
}

// ---------------- in_proj: x[b,t,h] (row-major) and xT[b,h,t] (scan layout) ----------------
__global__ void k_inproj_x(const float* __restrict__ in, const float* __restrict__ w,
                           const float* __restrict__ bias, float* __restrict__ x){
    int i = blockIdx.x*256+threadIdx.x;          // b*T*H + t*H + h
    int h = i & (H-1);
    int bt = i >> 10;
    x[i] = in[bt]*w[h] + bias[h];
}
__global__ void k_inproj_xT(const float* __restrict__ in, const float* __restrict__ w,
                            const float* __restrict__ bias, float* __restrict__ xT){
    int i = blockIdx.x*256+threadIdx.x;          // b*H*T + h*T + t
    int t = i & (TLEN-1);
    int bh = i >> 9;
    int h = bh & (H-1);
    int b = bh >> 10;
    xT[i] = in[b*TLEN + t]*w[h] + bias[h];
}

// ---------------- sequential scan: one wave per (b,h), lane n holds state n ----------------
__global__ __launch_bounds__(256) void k_scan(const float* __restrict__ xT, float* __restrict__ g,
        const float* __restrict__ dAr, const float* __restrict__ dAi,
        const float* __restrict__ dBr, const float* __restrict__ dBi,
        const float* __restrict__ Cre, const float* __restrict__ Cim,
        const float* __restrict__ Dv, int layer){
    int gtid = blockIdx.x*256 + threadIdx.x;
    int wid = gtid >> 6;                 // b*H + h
    int lane = gtid & 63;
    int h = wid & (H-1);
    int pi = (layer*H + h)*NST + lane;
    float ar = dAr[pi], ai = dAi[pi], br = dBr[pi], bi = dBi[pi];
    float cr = 2.0f*Cre[pi], ci = 2.0f*Cim[pi];
    float dv = Dv[layer*H + h];
    float sr = 0.f, si = 0.f;
    const float* xrow = xT + (size_t)wid*TLEN;
    float* grow = g + (size_t)wid*TLEN;
    for (int t0=0; t0<TLEN; t0+=64){
        float uvec = xrow[t0+lane];      // coalesced: 64 future u's, one per lane
        float ykeep = 0.f;
        #pragma unroll 16
        for (int tt=0; tt<64; ++tt){
            float u = __shfl(uvec, tt, 64);
            float nr = fmaf(ar,sr, fmaf(-ai,si, br*u));
            float ni = fmaf(ai,sr, fmaf( ar,si, bi*u));
            sr = nr; si = ni;
            float c = fmaf(cr,sr, -ci*si);
            #pragma unroll
            for (int m=1;m<64;m<<=1) c += __shfl_xor(c,m,64);
            float y = c + dv*u;          // factor 2 folded into cr/ci
            if (lane==tt) ykeep = y;
        }
        grow[t0+lane] = gelu_f(ykeep);   // gelu amortized over 64 steps
    }
}

// ---------------- encoder GEMM (fp32 vector) + bias + GLU fused ----------------
// g: (B,H,T) as A^T; W: (H,2H); out glu: (B,T,H). Block: 128 t-rows x 64 col-pairs.
#define BM 128
#define BPC 64
#define BK 16
__global__ __launch_bounds__(256) void k_gemm_glu(
        const float* __restrict__ g, const float* __restrict__ W,
        const float* __restrict__ bias2, float* __restrict__ glu){
    __shared__ float As[BK][BM+4];
    __shared__ float Bs[BK][2*BPC+4];
    int tid = threadIdx.x;
    int tx = tid & 15, ty = tid >> 4;
    int b  = blockIdx.y >> 2;
    int t0 = (blockIdx.y & 3) * BM;
    int c0 = blockIdx.x * BPC;
    const float* gA = g + (size_t)b*H*TLEN + t0;
    int lk = tid >> 4;
    int lm = (tid & 15) * 8;
    int bg = tid & 15;
    int bcol = (bg < 8) ? bg*8 : BPC + (bg-8)*8;
    size_t wcol = (bg < 8) ? (size_t)(c0 + bg*8) : (size_t)(H + c0 + (bg-8)*8);
    float acc_a[8][4], acc_b[8][4];
    #pragma unroll
    for (int r=0;r<8;r++){
        #pragma unroll
        for (int j=0;j<4;j++){ acc_a[r][j]=0.f; acc_b[r][j]=0.f; }
    }
    for (int k0=0;k0<H;k0+=BK){
        float4 a0 = *(const float4*)(gA + (size_t)(k0+lk)*TLEN + lm);
        float4 a1 = *(const float4*)(gA + (size_t)(k0+lk)*TLEN + lm + 4);
        const float* wsrc = W + (size_t)(k0+lk)*H2 + wcol;
        float4 w0 = *(const float4*)wsrc;
        float4 w1 = *(const float4*)(wsrc+4);
        __syncthreads();
        *(float4*)&As[lk][lm]   = a0;
        *(float4*)&As[lk][lm+4] = a1;
        *(float4*)&Bs[lk][bcol]   = w0;
        *(float4*)&Bs[lk][bcol+4] = w1;
        __syncthreads();
        #pragma unroll
        for (int k=0;k<BK;k++){
            float4 A0 = *(const float4*)&As[k][ty*8];
            float4 A1 = *(const float4*)&As[k][ty*8+4];
            float4 Ba = *(const float4*)&Bs[k][tx*4];
            float4 Bb = *(const float4*)&Bs[k][BPC + tx*4];
            float av[8] = {A0.x,A0.y,A0.z,A0.w,A1.x,A1.y,A1.z,A1.w};
            float pa[4] = {Ba.x,Ba.y,Ba.z,Ba.w};
            float pb[4] = {Bb.x,Bb.y,Bb.z,Bb.w};
            #pragma unroll
            for (int r=0;r<8;r++){
                #pragma unroll
                for (int j=0;j<4;j++){
                    acc_a[r][j] = fmaf(av[r], pa[j], acc_a[r][j]);
                    acc_b[r][j] = fmaf(av[r], pb[j], acc_b[r][j]);
                }
            }
        }
    }
    float ba_[4], bb_[4];
    #pragma unroll
    for (int j=0;j<4;j++){ ba_[j]=bias2[c0+tx*4+j]; bb_[j]=bias2[H+c0+tx*4+j]; }
    #pragma unroll
    for (int r=0;r<8;r++){
        int row = t0 + ty*8 + r;
        float ov[4];
        #pragma unroll
        for (int j=0;j<4;j++){
            float za = acc_a[r][j] + ba_[j];
            float zb = acc_b[r][j] + bb_[j];
            ov[j] = za * sigm_f(zb);
        }
        float4 o; o.x=ov[0]; o.y=ov[1]; o.z=ov[2]; o.w=ov[3];
        *(float4*)(glu + ((size_t)(b*TLEN + row))*H + c0 + tx*4) = o;
    }
}

// ---------------- LayerNorm over H per (b,t) row: out = LN(glu + res)*g + b ----------------
__global__ __launch_bounds__(256) void k_ln(const float* __restrict__ glu, const float* __restrict__ res,
        const float* __restrict__ gamma, const float* __restrict__ beta, float* __restrict__ outx){
    __shared__ float red[8];
    int row = blockIdx.x;
    int tid = threadIdx.x;
    float4 gv = *(const float4*)(glu + (size_t)row*H + tid*4);
    float4 rv = *(const float4*)(res + (size_t)row*H + tid*4);
    float x0=gv.x+rv.x, x1=gv.y+rv.y, x2=gv.z+rv.z, x3=gv.w+rv.w;
    float s = x0+x1+x2+x3;
    float q = x0*x0+x1*x1+x2*x2+x3*x3;
    #pragma unroll
    for (int m=32;m>=1;m>>=1){ s += __shfl_xor(s,m,64); q += __shfl_xor(q,m,64); }
    int wv = tid>>6;
    if ((tid&63)==0){ red[wv]=s; red[4+wv]=q; }
    __syncthreads();
    s = red[0]+red[1]+red[2]+red[3];
    q = red[4]+red[5]+red[6]+red[7];
    float m = s*(1.0f/H);
    float v = q*(1.0f/H) - m*m;
    float rstd = rsqrtf(v + 1e-5f);
    float4 gm = *(const float4*)(gamma + tid*4);
    float4 bt = *(const float4*)(beta + tid*4);
    float4 o;
    o.x = (x0-m)*rstd*gm.x + bt.x;
    o.y = (x1-m)*rstd*gm.y + bt.y;
    o.z = (x2-m)*rstd*gm.z + bt.z;
    o.w = (x3-m)*rstd*gm.w + bt.w;
    *(float4*)(outx + (size_t)row*H + tid*4) = o;
}

// ---------------- transpose (b,t,h) -> (b,h,t) ----------------
__global__ __launch_bounds__(256) void k_transpose(const float* __restrict__ x, float* __restrict__ xT){
    __shared__ float tile[32][33];
    int t0 = blockIdx.x*32, h0 = blockIdx.y*32, b = blockIdx.z;
    int tx = threadIdx.x & 31, ty = threadIdx.x >> 5;   // ty 0..7
    #pragma unroll
    for (int i=0;i<32;i+=8)
        tile[ty+i][tx] = x[((size_t)(b*TLEN + t0+ty+i))*H + h0+tx];
    __syncthreads();
    #pragma unroll
    for (int i=0;i<32;i+=8)
        xT[((size_t)(b*H + h0+ty+i))*TLEN + t0+tx] = tile[tx][ty+i];
}

__global__ void k_ctx(const float* __restrict__ x, float* __restrict__ ctx){
    int i = blockIdx.x*256+threadIdx.x;   // b*H+h
    int b = i>>10, h = i&(H-1);
    ctx[i] = x[((size_t)(b*TLEN + TLEN-1))*H + h];
}

// ---------------- decode: state update + y + gelu; one wave per (b,h) ----------------
__global__ __launch_bounds__(256) void k_dec_state(
        const float* __restrict__ dAr, const float* __restrict__ dAi,
        const float* __restrict__ dBr, const float* __restrict__ dBi,
        const float* __restrict__ Cre, const float* __restrict__ Cim,
        const float* __restrict__ Dv,
        float* __restrict__ sre, float* __restrict__ sim,
        const float* __restrict__ uin, int layer, int u_is_bits,
        float* __restrict__ ygel){
    int gtid = blockIdx.x*256 + threadIdx.x;
    int wid = gtid >> 6;
    int lane = gtid & 63;
    int b = wid >> 10, h = wid & (H-1);
    int pi = (layer*H + h)*NST + lane;
    size_t si = ((size_t)(layer*BSZ + b)*H + h)*NST + lane;
    float u = u_is_bits ? uin[b] : uin[b*H + h];
    float ar=dAr[pi], ai=dAi[pi], br=dBr[pi], bi=dBi[pi];
    float sr = sre[si], sI = sim[si];
    float nr = fmaf(ar,sr, fmaf(-ai,sI, br*u));
    float ni = fmaf(ai,sr, fmaf( ar,sI, bi*u));
    sre[si]=nr; sim[si]=ni;
    float c = Cre[pi]*nr - Cim[pi]*ni;
    #pragma unroll
    for (int m=1;m<64;m<<=1) c += __shfl_xor(c,m,64);
    if (lane==0){
        float y = 2.0f*c + Dv[layer*H+h]*u;
        ygel[b*H+h] = gelu_f(y);
    }
}

// ---------------- decode GEMM (32 x 2048 x 1024) + bias + GLU ----------------
// block: 8 col-pairs x 32 b; u staged through LDS (transposed), W streamed from L2.
__global__ __launch_bounds__(256) void k_dec_gemm(const float* __restrict__ ygel,
        const float* __restrict__ W, const float* __restrict__ bias2,
        float* __restrict__ glud){
    __shared__ float u_s[64][33];
    int tid = threadIdx.x;
    int p = blockIdx.x*8 + (tid>>5);
    int b = tid & 31;
    int sb = tid >> 3;
    int sk = (tid & 7) * 8;
    float aa=0.f, ab=0.f;
    for (int k0=0;k0<H;k0+=64){
        __syncthreads();
        float4 u0 = *(const float4*)(ygel + (size_t)sb*H + k0 + sk);
        float4 u1 = *(const float4*)(ygel + (size_t)sb*H + k0 + sk + 4);
        u_s[sk+0][sb]=u0.x; u_s[sk+1][sb]=u0.y; u_s[sk+2][sb]=u0.z; u_s[sk+3][sb]=u0.w;
        u_s[sk+4][sb]=u1.x; u_s[sk+5][sb]=u1.y; u_s[sk+6][sb]=u1.z; u_s[sk+7][sb]=u1.w;
        __syncthreads();
        #pragma unroll 8
        for (int k=0;k<64;k++){
            float wa = W[(size_t)(k0+k)*H2 + p];
            float wb = W[(size_t)(k0+k)*H2 + p + H];
            float u = u_s[k][b];
            aa = fmaf(u, wa, aa);
            ab = fmaf(u, wb, ab);
        }
    }
    float za = aa + bias2[p];
    float zb = ab + bias2[p+H];
    glud[b*H + p] = za * sigm_f(zb);
}

// ---------------- decode LN (+context+head+sigmoid+f32 out for last layer) ----------------
__global__ __launch_bounds__(256) void k_dec_ln(
        const float* __restrict__ glud, const float* __restrict__ bits_in,
        const float* __restrict__ gamma, const float* __restrict__ beta,
        float* __restrict__ dec,
        const float* __restrict__ ctx, const float* __restrict__ headw,
        const float* __restrict__ headb,
        float* __restrict__ bits, float* __restrict__ out,
        int step, int last){
    __shared__ float red[8];
    int b = blockIdx.x, tid = threadIdx.x;
    float4 gv = *(const float4*)(glud + b*H + tid*4);
    float u0 = bits_in[b];
    float x0,x1,x2,x3;
    if (step==0){ x0=gv.x+u0; x1=gv.y+u0; x2=gv.z+u0; x3=gv.w+u0; }
    else        { x0=2.f*gv.x; x1=2.f*gv.y; x2=2.f*gv.z; x3=2.f*gv.w; }
    float s = x0+x1+x2+x3, q = x0*x0+x1*x1+x2*x2+x3*x3;
    #pragma unroll
    for (int m=32;m>=1;m>>=1){ s+=__shfl_xor(s,m,64); q+=__shfl_xor(q,m,64); }
    int wv = tid>>6;
    if ((tid&63)==0){ red[wv]=s; red[4+wv]=q; }
    __syncthreads();
    s = red[0]+red[1]+red[2]+red[3];
    q = red[4]+red[5]+red[6]+red[7];
    float m = s*(1.f/H), v = q*(1.f/H)-m*m, rstd = rsqrtf(v+1e-5f);
    float4 gm = *(const float4*)(gamma + tid*4);
    float4 bt = *(const float4*)(beta + tid*4);
    float d0 = (x0-m)*rstd*gm.x+bt.x;
    float d1 = (x1-m)*rstd*gm.y+bt.y;
    float d2 = (x2-m)*rstd*gm.z+bt.z;
    float d3 = (x3-m)*rstd*gm.w+bt.w;
    if (!last){
        float4 o; o.x=d0;o.y=d1;o.z=d2;o.w=d3;
        *(float4*)(dec + b*H + tid*4) = o;
    } else {
        float4 cv = *(const float4*)(ctx + b*H + tid*4);
        d0+=cv.x; d1+=cv.y; d2+=cv.z; d3+=cv.w;
        float4 hw = *(const float4*)(headw + tid*4);
        float hp = d0*hw.x + d1*hw.y + d2*hw.z + d3*hw.w;
        #pragma unroll
        for (int mm=32;mm>=1;mm>>=1) hp += __shfl_xor(hp,mm,64);
        __syncthreads();
        if ((tid&63)==0) red[wv]=hp;
        __syncthreads();
        if (tid==0){
            float hs = red[0]+red[1]+red[2]+red[3] + headb[0];
            float bit = sigm_f(hs);
            bits[b] = bit;
            out[b*NSTEPS + step] = bit;   // f32 output per reference dtype
        }
    }
}

extern "C" void kernel_launch(void* const* d_in, const int* in_sizes, int n_in,
                              void* d_out, int out_size, void* d_ws, size_t ws_size,
                              hipStream_t stream) {
    const float* in_seq = (const float*)d_in[0];
    const float* inw  = (const float*)d_in[2];
    const float* inb  = (const float*)d_in[3];
    const float* log_dt = (const float*)d_in[4];
    const float* Are = (const float*)d_in[5];
    const float* Aim = (const float*)d_in[6];
    const float* Bre = (const float*)d_in[7];
    const float* Bim = (const float*)d_in[8];
    const float* Cre = (const float*)d_in[9];
    const float* Cim = (const float*)d_in[10];
    const float* Dv  = (const float*)d_in[11];
    const float* outw = (const float*)d_in[12];
    const float* outb = (const float*)d_in[13];
    const float* lng = (const float*)d_in[14];
    const float* lnb = (const float*)d_in[15];
    const float* headw = (const float*)d_in[16];
    const float* headb = (const float*)d_in[17];
    float* out = (float*)d_out;

    float* ws = (float*)d_ws;
    size_t off = 0;
    auto alloc = [&](size_t n){ float* p = ws + off; off += n; return p; };
    float* dAr = alloc((size_t)LAYN*H*NST);
    float* dAi = alloc((size_t)LAYN*H*NST);
    float* dBr = alloc((size_t)LAYN*H*NST);
    float* dBi = alloc((size_t)LAYN*H*NST);
    float* bufA = alloc((size_t)BSZ*TLEN*H);
    float* bufB = alloc((size_t)BSZ*TLEN*H);
    float* bufC = alloc((size_t)BSZ*TLEN*H);
    float* ctx = alloc((size_t)BSZ*H);
    float* sre = alloc((size_t)LAYN*BSZ*H*NST);
    float* sim = alloc((size_t)LAYN*BSZ*H*NST);
    float* ygel = alloc((size_t)BSZ*H);
    float* glud = alloc((size_t)BSZ*H);
    float* dec  = alloc((size_t)BSZ*H);
    float* bits = alloc(64);

    k_precompute<<<(LAYN*H*NST+255)/256, 256, 0, stream>>>(log_dt,Are,Aim,Bre,Bim,dAr,dAi,dBr,dBi);
    k_inproj_x <<<(BSZ*TLEN*H)/256, 256, 0, stream>>>(in_seq, inw, inb, bufA);
    k_inproj_xT<<<(BSZ*TLEN*H)/256, 256, 0, stream>>>(in_seq, inw, inb, bufB);

    // ---- layer 0: x=bufA (b,t,h), xT=bufB (b,h,t)
    k_scan<<<(BSZ*H*64)/256, 256, 0, stream>>>(bufB, bufC, dAr,dAi,dBr,dBi, Cre,Cim,Dv, 0);
    k_gemm_glu<<<dim3(16,128), 256, 0, stream>>>(bufC, outw, outb, bufB);
    k_ln<<<BSZ*TLEN, 256, 0, stream>>>(bufB, bufA, lng, lnb, bufC);        // x1 -> bufC
    k_transpose<<<dim3(16,32,32), 256, 0, stream>>>(bufC, bufA);           // x1T -> bufA

    // ---- layer 1
    k_scan<<<(BSZ*H*64)/256, 256, 0, stream>>>(bufA, bufB, dAr,dAi,dBr,dBi, Cre,Cim,Dv, 1);
    k_gemm_glu<<<dim3(16,128), 256, 0, stream>>>(bufB, outw + (size_t)H*H2, outb + H2, bufA);
    k_ln<<<BSZ*TLEN, 256, 0, stream>>>(bufA, bufC, lng+H, lnb+H, bufB);    // x2 -> bufB

    k_ctx<<<(BSZ*H)/256, 256, 0, stream>>>(bufB, ctx);

    hipMemsetAsync(sre, 0, sizeof(float)*(size_t)LAYN*BSZ*H*NST, stream);
    hipMemsetAsync(sim, 0, sizeof(float)*(size_t)LAYN*BSZ*H*NST, stream);
    hipMemsetAsync(bits, 0, sizeof(float)*64, stream);

    for (int i=0;i<NSTEPS;i++){
        // layer 0 (u = broadcast bit)
        k_dec_state<<<(BSZ*H*64)/256, 256, 0, stream>>>(dAr,dAi,dBr,dBi,Cre,Cim,Dv,
                                                        sre,sim, bits, 0, 1, ygel);
        k_dec_gemm<<<128, 256, 0, stream>>>(ygel, outw, outb, glud);
        k_dec_ln<<<BSZ, 256, 0, stream>>>(glud, bits, lng, lnb, dec, ctx, headw, headb,
                                          bits, out, i, 0);
        // layer 1 (u = dec)
        k_dec_state<<<(BSZ*H*64)/256, 256, 0, stream>>>(dAr,dAi,dBr,dBi,Cre,Cim,Dv,
                                                        sre,sim, dec, 1, 0, ygel);
        k_dec_gemm<<<128, 256, 0, stream>>>(ygel, outw + (size_t)H*H2, outb + H2, glud);
        k_dec_ln<<<BSZ, 256, 0, stream>>>(glud, bits, lng+H, lnb+H, dec, ctx, headw, headb,
                                          bits, out, i, 1);
    }
}

// Round 3
// 4562.195 us; speedup vs baseline: 1.4379x; 1.4379x over previous
//
#include <hip/hip_runtime.h>
#include <hip/hip_bf16.h>
#include <math.h>

#define H    1024
#define NST  64
#define LAYN 2
#define BSZ  32
#define TLEN 512
#define NSTEPS 16
#define H2   2048

__device__ __forceinline__ float gelu_f(float x){
    return 0.5f*x*(1.0f+erff(x*0.7071067811865475f));
}
__device__ __forceinline__ float sigm_f(float x){
    return 1.0f/(1.0f+expf(-x));
}

// ---------------- discretized SSM params: dA = exp(dt*A), dB = (dA-1)/A * B ----------------
__global__ void k_precompute(const float* __restrict__ log_dt,
                             const float* __restrict__ Are, const float* __restrict__ Aim,
                             const float* __restrict__ Bre, const float* __restrict__ Bim,
                             float* __restrict__ dAr, float* __restrict__ dAi,
                             float* __restrict__ dBr, float* __restrict__ dBi){
    int i = blockIdx.x*256 + threadIdx.x;
    if (i >= LAYN*H*NST) return;
    int lh = i / NST;
    float dt = expf(log_dt[lh]);
    float ar = Are[i], ai = Aim[i];
    float e  = expf(dt*ar);
    float sa, ca; sincosf(dt*ai, &sa, &ca);
    float dar = e*ca, dai = e*sa;
    float zr = dar-1.0f, zi = dai;
    float inv = 1.0f/(ar*ar + ai*ai);
    float wr = (zr*ar + zi*ai)*inv;
    float wi = (zi*ar - zr*ai)*inv;
    float br = Bre[i], bi = Bim[i];
    dAr[i]=dar; dAi[i]=dai;
    dBr[i]=wr*br - wi*bi;
    dBi[i]=wr*bi + wi*br;
}

// ---------------- in_proj: x[b,t,h] (row-major) and xT[b,h,t] (scan layout) ----------------
__global__ void k_inproj_x(const float* __restrict__ in, const float* __restrict__ w,
                           const float* __restrict__ bias, float* __restrict__ x){
    int i = blockIdx.x*256+threadIdx.x;          // b*T*H + t*H + h
    int h = i & (H-1);
    int bt = i >> 10;
    x[i] = in[bt]*w[h] + bias[h];
}
__global__ void k_inproj_xT(const float* __restrict__ in, const float* __restrict__ w,
                            const float* __restrict__ bias, float* __restrict__ xT){
    int i = blockIdx.x*256+threadIdx.x;          // b*H*T + h*T + t
    int t = i & (TLEN-1);
    int bh = i >> 9;
    int h = bh & (H-1);
    int b = bh >> 10;
    xT[i] = in[b*TLEN + t]*w[h] + bias[h];
}

// ---------------- S4 conv kernel gen: K[l,h,t] = 2*Re(sum_n c_n dA_n^t dB_n) ----------------
// One wave per (l,h). Lane n advances w = 2*c*dB by *dA each step; per-16-step
// LDS transpose-reduce over the 64 lanes (no per-step shuffle chains).
__global__ __launch_bounds__(64) void k_genK(
        const float* __restrict__ dAr, const float* __restrict__ dAi,
        const float* __restrict__ dBr, const float* __restrict__ dBi,
        const float* __restrict__ Cre, const float* __restrict__ Cim,
        float* __restrict__ Kbuf){
    __shared__ float trans[16][65];
    int lh = blockIdx.x;
    int lane = threadIdx.x;
    int pi = lh*NST + lane;
    float ar=dAr[pi], ai=dAi[pi];
    float br=dBr[pi], bi=dBi[pi];
    float cr=2.f*Cre[pi], ci=2.f*Cim[pi];
    float wr = cr*br - ci*bi;      // w = 2*c*dB
    float wi = cr*bi + ci*br;
    float* Krow = Kbuf + (size_t)lh*TLEN;
    int r = lane>>2, q = lane&3;
    for (int c=0;c<TLEN/16;c++){
        #pragma unroll
        for (int i=0;i<16;i++){
            trans[i][lane] = wr;                    // value for t = c*16+i
            float nr = fmaf(wr,ar, -wi*ai);
            float ni = fmaf(wr,ai,  wi*ar);
            wr=nr; wi=ni;
        }
        __syncthreads();
        float s = 0.f;
        #pragma unroll
        for (int m=0;m<16;m++) s += trans[r][q*16+m];
        s += __shfl_xor(s,1,64);
        s += __shfl_xor(s,2,64);
        if (q==0) Krow[c*16 + r] = s;
        __syncthreads();
    }
}

// ---------------- causal Toeplitz conv + D*u + gelu ----------------
// y[b,h,t] = sum_{j<=t} K[h][t-j]*u[b,h,j] + D[h]*u[b,h,t]; g = gelu(y).
// Block: one h, 256-t tile, all 32 b. Thread: 8 consecutive t x 4 b outer product.
#define CTT 256
#define CJT 64
__global__ __launch_bounds__(256) void k_conv(
        const float* __restrict__ u,    // (B,H,T)
        const float* __restrict__ Kbuf, // (L,H,T)
        const float* __restrict__ Dv,
        float* __restrict__ g,          // (B,H,T)
        int layer){
    __shared__ float u_s[CJT][33];
    __shared__ float Ks[CTT+CJT];
    int h  = blockIdx.y;
    int t0 = blockIdx.x * CTT;
    int tid = threadIdx.x;
    int bg = tid & 7;      // b = bg*4 .. +4
    int tg = tid >> 3;     // t = t0 + tg*8 .. +8
    const float* Krow = Kbuf + ((size_t)layer*H + h)*TLEN;
    float acc[8][4];
    #pragma unroll
    for (int i=0;i<8;i++){
        #pragma unroll
        for (int b=0;b<4;b++) acc[i][b]=0.f;
    }
    int ntile = t0/CJT + CTT/CJT;
    for (int jt=0; jt<ntile; jt++){
        int j0 = jt*CJT;
        __syncthreads();
        for (int i=tid; i<CTT+CJT; i+=256){
            int d = t0 - j0 - (CJT-1) + i;
            Ks[i] = (d>=0) ? Krow[d] : 0.f;        // d <= 511 always
        }
        {
            int jj = tid & 63, bq = tid >> 6;
            #pragma unroll
            for (int p=0;p<8;p++){
                int b = bq + p*4;
                u_s[jj][b] = u[((size_t)b*H + h)*TLEN + j0 + jj];
            }
        }
        __syncthreads();
        #pragma unroll 8
        for (int j=0;j<CJT;j++){
            float4 ub = *(const float4*)&u_s[j][bg*4];
            int base = tg*8 + (CJT-1) - j;
            float kv[8];
            #pragma unroll
            for (int i=0;i<8;i++) kv[i] = Ks[base+i];
            #pragma unroll
            for (int i=0;i<8;i++){
                acc[i][0] = fmaf(kv[i], ub.x, acc[i][0]);
                acc[i][1] = fmaf(kv[i], ub.y, acc[i][1]);
                acc[i][2] = fmaf(kv[i], ub.z, acc[i][2]);
                acc[i][3] = fmaf(kv[i], ub.w, acc[i][3]);
            }
        }
    }
    float dv = Dv[layer*H + h];
    int tb = t0 + tg*8;
    #pragma unroll
    for (int b=0;b<4;b++){
        int bb = bg*4 + b;
        const float* urow = u + ((size_t)bb*H + h)*TLEN + tb;
        float* grow = g + ((size_t)bb*H + h)*TLEN + tb;
        float4 u0 = *(const float4*)urow;
        float4 u1 = *(const float4*)(urow+4);
        float4 o0, o1;
        o0.x = gelu_f(fmaf(dv,u0.x, acc[0][b]));
        o0.y = gelu_f(fmaf(dv,u0.y, acc[1][b]));
        o0.z = gelu_f(fmaf(dv,u0.z, acc[2][b]));
        o0.w = gelu_f(fmaf(dv,u0.w, acc[3][b]));
        o1.x = gelu_f(fmaf(dv,u1.x, acc[4][b]));
        o1.y = gelu_f(fmaf(dv,u1.y, acc[5][b]));
        o1.z = gelu_f(fmaf(dv,u1.z, acc[6][b]));
        o1.w = gelu_f(fmaf(dv,u1.w, acc[7][b]));
        *(float4*)grow     = o0;
        *(float4*)(grow+4) = o1;
    }
}

// ---------------- encoder GEMM (fp32 vector) + bias + GLU fused ----------------
// g: (B,H,T) as A^T; W: (H,2H); out glu: (B,T,H). Block: 128 t-rows x 64 col-pairs.
#define BM 128
#define BPC 64
#define BK 16
__global__ __launch_bounds__(256) void k_gemm_glu(
        const float* __restrict__ g, const float* __restrict__ W,
        const float* __restrict__ bias2, float* __restrict__ glu){
    __shared__ float As[BK][BM+4];
    __shared__ float Bs[BK][2*BPC+4];
    int tid = threadIdx.x;
    int tx = tid & 15, ty = tid >> 4;
    int b  = blockIdx.y >> 2;
    int t0 = (blockIdx.y & 3) * BM;
    int c0 = blockIdx.x * BPC;
    const float* gA = g + (size_t)b*H*TLEN + t0;
    int lk = tid >> 4;
    int lm = (tid & 15) * 8;
    int bg = tid & 15;
    int bcol = (bg < 8) ? bg*8 : BPC + (bg-8)*8;
    size_t wcol = (bg < 8) ? (size_t)(c0 + bg*8) : (size_t)(H + c0 + (bg-8)*8);
    float acc_a[8][4], acc_b[8][4];
    #pragma unroll
    for (int r=0;r<8;r++){
        #pragma unroll
        for (int j=0;j<4;j++){ acc_a[r][j]=0.f; acc_b[r][j]=0.f; }
    }
    for (int k0=0;k0<H;k0+=BK){
        float4 a0 = *(const float4*)(gA + (size_t)(k0+lk)*TLEN + lm);
        float4 a1 = *(const float4*)(gA + (size_t)(k0+lk)*TLEN + lm + 4);
        const float* wsrc = W + (size_t)(k0+lk)*H2 + wcol;
        float4 w0 = *(const float4*)wsrc;
        float4 w1 = *(const float4*)(wsrc+4);
        __syncthreads();
        *(float4*)&As[lk][lm]   = a0;
        *(float4*)&As[lk][lm+4] = a1;
        *(float4*)&Bs[lk][bcol]   = w0;
        *(float4*)&Bs[lk][bcol+4] = w1;
        __syncthreads();
        #pragma unroll
        for (int k=0;k<BK;k++){
            float4 A0 = *(const float4*)&As[k][ty*8];
            float4 A1 = *(const float4*)&As[k][ty*8+4];
            float4 Ba = *(const float4*)&Bs[k][tx*4];
            float4 Bb = *(const float4*)&Bs[k][BPC + tx*4];
            float av[8] = {A0.x,A0.y,A0.z,A0.w,A1.x,A1.y,A1.z,A1.w};
            float pa[4] = {Ba.x,Ba.y,Ba.z,Ba.w};
            float pb[4] = {Bb.x,Bb.y,Bb.z,Bb.w};
            #pragma unroll
            for (int r=0;r<8;r++){
                #pragma unroll
                for (int j=0;j<4;j++){
                    acc_a[r][j] = fmaf(av[r], pa[j], acc_a[r][j]);
                    acc_b[r][j] = fmaf(av[r], pb[j], acc_b[r][j]);
                }
            }
        }
    }
    float ba_[4], bb_[4];
    #pragma unroll
    for (int j=0;j<4;j++){ ba_[j]=bias2[c0+tx*4+j]; bb_[j]=bias2[H+c0+tx*4+j]; }
    #pragma unroll
    for (int r=0;r<8;r++){
        int row = t0 + ty*8 + r;
        float ov[4];
        #pragma unroll
        for (int j=0;j<4;j++){
            float za = acc_a[r][j] + ba_[j];
            float zb = acc_b[r][j] + bb_[j];
            ov[j] = za * sigm_f(zb);
        }
        float4 o; o.x=ov[0]; o.y=ov[1]; o.z=ov[2]; o.w=ov[3];
        *(float4*)(glu + ((size_t)(b*TLEN + row))*H + c0 + tx*4) = o;
    }
}

// ---------------- LayerNorm over H per (b,t) row: out = LN(glu + res)*g + b ----------------
__global__ __launch_bounds__(256) void k_ln(const float* __restrict__ glu, const float* __restrict__ res,
        const float* __restrict__ gamma, const float* __restrict__ beta, float* __restrict__ outx){
    __shared__ float red[8];
    int row = blockIdx.x;
    int tid = threadIdx.x;
    float4 gv = *(const float4*)(glu + (size_t)row*H + tid*4);
    float4 rv = *(const float4*)(res + (size_t)row*H + tid*4);
    float x0=gv.x+rv.x, x1=gv.y+rv.y, x2=gv.z+rv.z, x3=gv.w+rv.w;
    float s = x0+x1+x2+x3;
    float q = x0*x0+x1*x1+x2*x2+x3*x3;
    #pragma unroll
    for (int m=32;m>=1;m>>=1){ s += __shfl_xor(s,m,64); q += __shfl_xor(q,m,64); }
    int wv = tid>>6;
    if ((tid&63)==0){ red[wv]=s; red[4+wv]=q; }
    __syncthreads();
    s = red[0]+red[1]+red[2]+red[3];
    q = red[4]+red[5]+red[6]+red[7];
    float m = s*(1.0f/H);
    float v = q*(1.0f/H) - m*m;
    float rstd = rsqrtf(v + 1e-5f);
    float4 gm = *(const float4*)(gamma + tid*4);
    float4 bt = *(const float4*)(beta + tid*4);
    float4 o;
    o.x = (x0-m)*rstd*gm.x + bt.x;
    o.y = (x1-m)*rstd*gm.y + bt.y;
    o.z = (x2-m)*rstd*gm.z + bt.z;
    o.w = (x3-m)*rstd*gm.w + bt.w;
    *(float4*)(outx + (size_t)row*H + tid*4) = o;
}

// ---------------- transpose (b,t,h) -> (b,h,t) ----------------
__global__ __launch_bounds__(256) void k_transpose(const float* __restrict__ x, float* __restrict__ xT){
    __shared__ float tile[32][33];
    int t0 = blockIdx.x*32, h0 = blockIdx.y*32, b = blockIdx.z;
    int tx = threadIdx.x & 31, ty = threadIdx.x >> 5;   // ty 0..7
    #pragma unroll
    for (int i=0;i<32;i+=8)
        tile[ty+i][tx] = x[((size_t)(b*TLEN + t0+ty+i))*H + h0+tx];
    __syncthreads();
    #pragma unroll
    for (int i=0;i<32;i+=8)
        xT[((size_t)(b*H + h0+ty+i))*TLEN + t0+tx] = tile[tx][ty+i];
}

__global__ void k_ctx(const float* __restrict__ x, float* __restrict__ ctx){
    int i = blockIdx.x*256+threadIdx.x;   // b*H+h
    int b = i>>10, h = i&(H-1);
    ctx[i] = x[((size_t)(b*TLEN + TLEN-1))*H + h];
}

// ---------------- decode: state update + y + gelu; one wave per (b,h) ----------------
__global__ __launch_bounds__(256) void k_dec_state(
        const float* __restrict__ dAr, const float* __restrict__ dAi,
        const float* __restrict__ dBr, const float* __restrict__ dBi,
        const float* __restrict__ Cre, const float* __restrict__ Cim,
        const float* __restrict__ Dv,
        float* __restrict__ sre, float* __restrict__ sim,
        const float* __restrict__ uin, int layer, int u_is_bits,
        float* __restrict__ ygel){
    int gtid = blockIdx.x*256 + threadIdx.x;
    int wid = gtid >> 6;
    int lane = gtid & 63;
    int b = wid >> 10, h = wid & (H-1);
    int pi = (layer*H + h)*NST + lane;
    size_t si = ((size_t)(layer*BSZ + b)*H + h)*NST + lane;
    float u = u_is_bits ? uin[b] : uin[b*H + h];
    float ar=dAr[pi], ai=dAi[pi], br=dBr[pi], bi=dBi[pi];
    float sr = sre[si], sI = sim[si];
    float nr = fmaf(ar,sr, fmaf(-ai,sI, br*u));
    float ni = fmaf(ai,sr, fmaf( ar,sI, bi*u));
    sre[si]=nr; sim[si]=ni;
    float c = Cre[pi]*nr - Cim[pi]*ni;
    #pragma unroll
    for (int m=1;m<64;m<<=1) c += __shfl_xor(c,m,64);
    if (lane==0){
        float y = 2.0f*c + Dv[layer*H+h]*u;
        ygel[b*H+h] = gelu_f(y);
    }
}

// ---------------- decode GEMM (32 x 2048 x 1024) + bias + GLU ----------------
__global__ __launch_bounds__(256) void k_dec_gemm(const float* __restrict__ ygel,
        const float* __restrict__ W, const float* __restrict__ bias2,
        float* __restrict__ glud){
    __shared__ float u_s[64][33];
    int tid = threadIdx.x;
    int p = blockIdx.x*8 + (tid>>5);
    int b = tid & 31;
    int sb = tid >> 3;
    int sk = (tid & 7) * 8;
    float aa=0.f, ab=0.f;
    for (int k0=0;k0<H;k0+=64){
        __syncthreads();
        float4 u0 = *(const float4*)(ygel + (size_t)sb*H + k0 + sk);
        float4 u1 = *(const float4*)(ygel + (size_t)sb*H + k0 + sk + 4);
        u_s[sk+0][sb]=u0.x; u_s[sk+1][sb]=u0.y; u_s[sk+2][sb]=u0.z; u_s[sk+3][sb]=u0.w;
        u_s[sk+4][sb]=u1.x; u_s[sk+5][sb]=u1.y; u_s[sk+6][sb]=u1.z; u_s[sk+7][sb]=u1.w;
        __syncthreads();
        #pragma unroll 8
        for (int k=0;k<64;k++){
            float wa = W[(size_t)(k0+k)*H2 + p];
            float wb = W[(size_t)(k0+k)*H2 + p + H];
            float u = u_s[k][b];
            aa = fmaf(u, wa, aa);
            ab = fmaf(u, wb, ab);
        }
    }
    float za = aa + bias2[p];
    float zb = ab + bias2[p+H];
    glud[b*H + p] = za * sigm_f(zb);
}

// ---------------- decode LN (+context+head+sigmoid+f32 out for last layer) ----------------
__global__ __launch_bounds__(256) void k_dec_ln(
        const float* __restrict__ glud, const float* __restrict__ bits_in,
        const float* __restrict__ gamma, const float* __restrict__ beta,
        float* __restrict__ dec,
        const float* __restrict__ ctx, const float* __restrict__ headw,
        const float* __restrict__ headb,
        float* __restrict__ bits, float* __restrict__ out,
        int step, int last){
    __shared__ float red[8];
    int b = blockIdx.x, tid = threadIdx.x;
    float4 gv = *(const float4*)(glud + b*H + tid*4);
    float u0 = bits_in[b];
    float x0,x1,x2,x3;
    if (step==0){ x0=gv.x+u0; x1=gv.y+u0; x2=gv.z+u0; x3=gv.w+u0; }
    else        { x0=2.f*gv.x; x1=2.f*gv.y; x2=2.f*gv.z; x3=2.f*gv.w; }
    float s = x0+x1+x2+x3, q = x0*x0+x1*x1+x2*x2+x3*x3;
    #pragma unroll
    for (int m=32;m>=1;m>>=1){ s+=__shfl_xor(s,m,64); q+=__shfl_xor(q,m,64); }
    int wv = tid>>6;
    if ((tid&63)==0){ red[wv]=s; red[4+wv]=q; }
    __syncthreads();
    s = red[0]+red[1]+red[2]+red[3];
    q = red[4]+red[5]+red[6]+red[7];
    float m = s*(1.f/H), v = q*(1.f/H)-m*m, rstd = rsqrtf(v+1e-5f);
    float4 gm = *(const float4*)(gamma + tid*4);
    float4 bt = *(const float4*)(beta + tid*4);
    float d0 = (x0-m)*rstd*gm.x+bt.x;
    float d1 = (x1-m)*rstd*gm.y+bt.y;
    float d2 = (x2-m)*rstd*gm.z+bt.z;
    float d3 = (x3-m)*rstd*gm.w+bt.w;
    if (!last){
        float4 o; o.x=d0;o.y=d1;o.z=d2;o.w=d3;
        *(float4*)(dec + b*H + tid*4) = o;
    } else {
        float4 cv = *(const float4*)(ctx + b*H + tid*4);
        d0+=cv.x; d1+=cv.y; d2+=cv.z; d3+=cv.w;
        float4 hw = *(const float4*)(headw + tid*4);
        float hp = d0*hw.x + d1*hw.y + d2*hw.z + d3*hw.w;
        #pragma unroll
        for (int mm=32;mm>=1;mm>>=1) hp += __shfl_xor(hp,mm,64);
        __syncthreads();
        if ((tid&63)==0) red[wv]=hp;
        __syncthreads();
        if (tid==0){
            float hs = red[0]+red[1]+red[2]+red[3] + headb[0];
            float bit = sigm_f(hs);
            bits[b] = bit;
            out[b*NSTEPS + step] = bit;
        }
    }
}

extern "C" void kernel_launch(void* const* d_in, const int* in_sizes, int n_in,
                              void* d_out, int out_size, void* d_ws, size_t ws_size,
                              hipStream_t stream) {
    const float* in_seq = (const float*)d_in[0];
    const float* inw  = (const float*)d_in[2];
    const float* inb  = (const float*)d_in[3];
    const float* log_dt = (const float*)d_in[4];
    const float* Are = (const float*)d_in[5];
    const float* Aim = (const float*)d_in[6];
    const float* Bre = (const float*)d_in[7];
    const float* Bim = (const float*)d_in[8];
    const float* Cre = (const float*)d_in[9];
    const float* Cim = (const float*)d_in[10];
    const float* Dv  = (const float*)d_in[11];
    const float* outw = (const float*)d_in[12];
    const float* outb = (const float*)d_in[13];
    const float* lng = (const float*)d_in[14];
    const float* lnb = (const float*)d_in[15];
    const float* headw = (const float*)d_in[16];
    const float* headb = (const float*)d_in[17];
    float* out = (float*)d_out;

    float* ws = (float*)d_ws;
    size_t off = 0;
    auto alloc = [&](size_t n){ float* p = ws + off; off += n; return p; };
    float* dAr = alloc((size_t)LAYN*H*NST);
    float* dAi = alloc((size_t)LAYN*H*NST);
    float* dBr = alloc((size_t)LAYN*H*NST);
    float* dBi = alloc((size_t)LAYN*H*NST);
    float* Kbuf = alloc((size_t)LAYN*H*TLEN);
    float* bufA = alloc((size_t)BSZ*TLEN*H);
    float* bufB = alloc((size_t)BSZ*TLEN*H);
    float* bufC = alloc((size_t)BSZ*TLEN*H);
    float* ctx = alloc((size_t)BSZ*H);
    float* sre = alloc((size_t)LAYN*BSZ*H*NST);
    float* sim = alloc((size_t)LAYN*BSZ*H*NST);
    float* ygel = alloc((size_t)BSZ*H);
    float* glud = alloc((size_t)BSZ*H);
    float* dec  = alloc((size_t)BSZ*H);
    float* bits = alloc(64);

    k_precompute<<<(LAYN*H*NST+255)/256, 256, 0, stream>>>(log_dt,Are,Aim,Bre,Bim,dAr,dAi,dBr,dBi);
    k_genK<<<LAYN*H, 64, 0, stream>>>(dAr,dAi,dBr,dBi,Cre,Cim,Kbuf);
    k_inproj_x <<<(BSZ*TLEN*H)/256, 256, 0, stream>>>(in_seq, inw, inb, bufA);
    k_inproj_xT<<<(BSZ*TLEN*H)/256, 256, 0, stream>>>(in_seq, inw, inb, bufB);

    // ---- layer 0: x=bufA (b,t,h), xT=bufB (b,h,t)
    k_conv<<<dim3(TLEN/CTT, H), 256, 0, stream>>>(bufB, Kbuf, Dv, bufC, 0);
    k_gemm_glu<<<dim3(16,128), 256, 0, stream>>>(bufC, outw, outb, bufB);
    k_ln<<<BSZ*TLEN, 256, 0, stream>>>(bufB, bufA, lng, lnb, bufC);        // x1 -> bufC
    k_transpose<<<dim3(16,32,32), 256, 0, stream>>>(bufC, bufA);           // x1T -> bufA

    // ---- layer 1
    k_conv<<<dim3(TLEN/CTT, H), 256, 0, stream>>>(bufA, Kbuf, Dv, bufB, 1);
    k_gemm_glu<<<dim3(16,128), 256, 0, stream>>>(bufB, outw + (size_t)H*H2, outb + H2, bufA);
    k_ln<<<BSZ*TLEN, 256, 0, stream>>>(bufA, bufC, lng+H, lnb+H, bufB);    // x2 -> bufB

    k_ctx<<<(BSZ*H)/256, 256, 0, stream>>>(bufB, ctx);

    hipMemsetAsync(sre, 0, sizeof(float)*(size_t)LAYN*BSZ*H*NST, stream);
    hipMemsetAsync(sim, 0, sizeof(float)*(size_t)LAYN*BSZ*H*NST, stream);
    hipMemsetAsync(bits, 0, sizeof(float)*64, stream);

    for (int i=0;i<NSTEPS;i++){
        // layer 0 (u = broadcast bit)
        k_dec_state<<<(BSZ*H*64)/256, 256, 0, stream>>>(dAr,dAi,dBr,dBi,Cre,Cim,Dv,
                                                        sre,sim, bits, 0, 1, ygel);
        k_dec_gemm<<<128, 256, 0, stream>>>(ygel, outw, outb, glud);
        k_dec_ln<<<BSZ, 256, 0, stream>>>(glud, bits, lng, lnb, dec, ctx, headw, headb,
                                          bits, out, i, 0);
        // layer 1 (u = dec)
        k_dec_state<<<(BSZ*H*64)/256, 256, 0, stream>>>(dAr,dAi,dBr,dBi,Cre,Cim,Dv,
                                                        sre,sim, dec, 1, 0, ygel);
        k_dec_gemm<<<128, 256, 0, stream>>>(ygel, outw + (size_t)H*H2, outb + H2, glud);
        k_dec_ln<<<BSZ, 256, 0, stream>>>(glud, bits, lng+H, lnb+H, dec, ctx, headw, headb,
                                          bits, out, i, 1);
    }
}

// Round 5
// 3231.116 us; speedup vs baseline: 2.0302x; 1.4120x over previous
//
#include <hip/hip_runtime.h>
#include <hip/hip_bf16.h>
#include <math.h>

#define H    1024
#define NST  64
#define LAYN 2
#define BSZ  32
#define TLEN 512
#define NSTEPS 16
#define H2   2048

typedef __attribute__((ext_vector_type(8))) short bf16x8;
typedef __attribute__((ext_vector_type(4))) float f32x4;

__device__ __forceinline__ float gelu_f(float x){
    return 0.5f*x*(1.0f+erff(x*0.7071067811865475f));
}
__device__ __forceinline__ float sigm_f(float x){
    return 1.0f/(1.0f+expf(-x));
}
__device__ __forceinline__ short bfbits(float x){
    __hip_bfloat16 h = __float2bfloat16(x);
    return *(short*)&h;
}
__device__ __forceinline__ void gload16(const void* g, void* l){
    __builtin_amdgcn_global_load_lds((const __attribute__((address_space(1))) void*)g,
                                     (__attribute__((address_space(3))) void*)l, 16, 0, 0);
}

// ---------------- discretized SSM params ----------------
__global__ void k_precompute(const float* __restrict__ log_dt,
                             const float* __restrict__ Are, const float* __restrict__ Aim,
                             const float* __restrict__ Bre, const float* __restrict__ Bim,
                             float* __restrict__ dAr, float* __restrict__ dAi,
                             float* __restrict__ dBr, float* __restrict__ dBi){
    int i = blockIdx.x*256 + threadIdx.x;
    if (i >= LAYN*H*NST) return;
    int lh = i / NST;
    float dt = expf(log_dt[lh]);
    float ar = Are[i], ai = Aim[i];
    float e  = expf(dt*ar);
    float sa, ca; sincosf(dt*ai, &sa, &ca);
    float dar = e*ca, dai = e*sa;
    float zr = dar-1.0f, zi = dai;
    float inv = 1.0f/(ar*ar + ai*ai);
    float wr = (zr*ar + zi*ai)*inv;
    float wi = (zi*ar - zr*ai)*inv;
    float br = Bre[i], bi = Bim[i];
    dAr[i]=dar; dAi[i]=dai;
    dBr[i]=wr*br - wi*bi;
    dBi[i]=wr*bi + wi*br;
}

// ---------------- in_proj ----------------
__global__ void k_inproj_x(const float* __restrict__ in, const float* __restrict__ w,
                           const float* __restrict__ bias, float* __restrict__ x){
    int i = blockIdx.x*256+threadIdx.x;          // b*T*H + t*H + h
    int h = i & (H-1);
    int bt = i >> 10;
    x[i] = in[bt]*w[h] + bias[h];
}
__global__ void k_inproj_xT(const float* __restrict__ in, const float* __restrict__ w,
                            const float* __restrict__ bias, float* __restrict__ xT){
    int i = blockIdx.x*256+threadIdx.x;          // b*H*T + h*T + t
    int t = i & (TLEN-1);
    int bh = i >> 9;
    int h = bh & (H-1);
    int b = bh >> 10;
    xT[i] = in[b*TLEN + t]*w[h] + bias[h];
}

// ---------------- S4 conv kernel gen ----------------
__global__ __launch_bounds__(64) void k_genK(
        const float* __restrict__ dAr, const float* __restrict__ dAi,
        const float* __restrict__ dBr, const float* __restrict__ dBi,
        const float* __restrict__ Cre, const float* __restrict__ Cim,
        float* __restrict__ Kbuf){
    __shared__ float trans[16][65];
    int lh = blockIdx.x;
    int lane = threadIdx.x;
    int pi = lh*NST + lane;
    float ar=dAr[pi], ai=dAi[pi];
    float br=dBr[pi], bi=dBi[pi];
    float cr=2.f*Cre[pi], ci=2.f*Cim[pi];
    float wr = cr*br - ci*bi;
    float wi = cr*bi + ci*br;
    float* Krow = Kbuf + (size_t)lh*TLEN;
    int r = lane>>2, q = lane&3;
    for (int c=0;c<TLEN/16;c++){
        #pragma unroll
        for (int i=0;i<16;i++){
            trans[i][lane] = wr;
            float nr = fmaf(wr,ar, -wi*ai);
            float ni = fmaf(wr,ai,  wi*ar);
            wr=nr; wi=ni;
        }
        __syncthreads();
        float s = 0.f;
        #pragma unroll
        for (int m=0;m<16;m++) s += trans[r][q*16+m];
        s += __shfl_xor(s,1,64);
        s += __shfl_xor(s,2,64);
        if (q==0) Krow[c*16 + r] = s;
        __syncthreads();
    }
}

// ---------------- causal Toeplitz conv + D*u + gelu; bf16 (B,H,T) out ----------------
#define CTT 256
#define CJT 64
__global__ __launch_bounds__(256) void k_conv(
        const float* __restrict__ u,            // (B,H,T) f32
        const float* __restrict__ Kbuf,         // (L,H,T)
        const float* __restrict__ Dv,
        __hip_bfloat16* __restrict__ g,         // (B,H,T) bf16
        int layer){
    __shared__ float u_s[CJT][33];
    __shared__ float Ks[CTT+CJT];
    int h  = blockIdx.y;
    int t0 = blockIdx.x * CTT;
    int tid = threadIdx.x;
    int bg = tid & 7;
    int tg = tid >> 3;
    const float* Krow = Kbuf + ((size_t)layer*H + h)*TLEN;
    float acc[8][4];
    #pragma unroll
    for (int i=0;i<8;i++){
        #pragma unroll
        for (int b=0;b<4;b++) acc[i][b]=0.f;
    }
    int ntile = t0/CJT + CTT/CJT;
    for (int jt=0; jt<ntile; jt++){
        int j0 = jt*CJT;
        __syncthreads();
        for (int i=tid; i<CTT+CJT; i+=256){
            int d = t0 - j0 - (CJT-1) + i;
            Ks[i] = (d>=0) ? Krow[d] : 0.f;
        }
        {
            int jj = tid & 63, bq = tid >> 6;
            #pragma unroll
            for (int p=0;p<8;p++){
                int b = bq + p*4;
                u_s[jj][b] = u[((size_t)b*H + h)*TLEN + j0 + jj];
            }
        }
        __syncthreads();
        #pragma unroll 8
        for (int j=0;j<CJT;j++){
            float4 ub = *(const float4*)&u_s[j][bg*4];
            int base = tg*8 + (CJT-1) - j;
            float kv[8];
            #pragma unroll
            for (int i=0;i<8;i++) kv[i] = Ks[base+i];
            #pragma unroll
            for (int i=0;i<8;i++){
                acc[i][0] = fmaf(kv[i], ub.x, acc[i][0]);
                acc[i][1] = fmaf(kv[i], ub.y, acc[i][1]);
                acc[i][2] = fmaf(kv[i], ub.z, acc[i][2]);
                acc[i][3] = fmaf(kv[i], ub.w, acc[i][3]);
            }
        }
    }
    float dv = Dv[layer*H + h];
    int tb = t0 + tg*8;
    #pragma unroll
    for (int b=0;b<4;b++){
        int bb = bg*4 + b;
        const float* urow = u + ((size_t)bb*H + h)*TLEN + tb;
        float4 u0 = *(const float4*)urow;
        float4 u1 = *(const float4*)(urow+4);
        bf16x8 o;
        o[0] = bfbits(gelu_f(fmaf(dv,u0.x, acc[0][b])));
        o[1] = bfbits(gelu_f(fmaf(dv,u0.y, acc[1][b])));
        o[2] = bfbits(gelu_f(fmaf(dv,u0.z, acc[2][b])));
        o[3] = bfbits(gelu_f(fmaf(dv,u0.w, acc[3][b])));
        o[4] = bfbits(gelu_f(fmaf(dv,u1.x, acc[4][b])));
        o[5] = bfbits(gelu_f(fmaf(dv,u1.y, acc[5][b])));
        o[6] = bfbits(gelu_f(fmaf(dv,u1.z, acc[6][b])));
        o[7] = bfbits(gelu_f(fmaf(dv,u1.w, acc[7][b])));
        *(bf16x8*)(g + ((size_t)bb*H + h)*TLEN + tb) = o;
    }
}

// ---------------- bf16 transpose (B,H,T) -> (B,T,H) ----------------
__global__ __launch_bounds__(256) void k_trcast_bf(const __hip_bfloat16* __restrict__ x,
                                                   __hip_bfloat16* __restrict__ y){
    __shared__ __hip_bfloat16 tile[32][34];
    int t0 = blockIdx.x*32, h0 = blockIdx.y*32, b = blockIdx.z;
    int tx = threadIdx.x & 31, ty = threadIdx.x >> 5;
    #pragma unroll
    for (int i=0;i<32;i+=8)
        tile[ty+i][tx] = x[((size_t)(b*H + h0+ty+i))*TLEN + t0+tx];
    __syncthreads();
    #pragma unroll
    for (int i=0;i<32;i+=8)
        y[((size_t)(b*TLEN + t0+ty+i))*H + h0+tx] = tile[tx][ty+i];
}

// ---------------- W (L,H,2H) f32 -> Wt (L,2H,H) bf16 ----------------
__global__ __launch_bounds__(256) void k_wtr(const float* __restrict__ W,
                                             __hip_bfloat16* __restrict__ Wt){
    __shared__ float tile[32][33];
    int n0 = blockIdx.x*32, k0 = blockIdx.y*32, l = blockIdx.z;
    const float* Wl = W + (size_t)l*H*H2;
    __hip_bfloat16* Wtl = Wt + (size_t)l*H*H2;
    int tx = threadIdx.x & 31, ty = threadIdx.x >> 5;
    #pragma unroll
    for (int i=0;i<32;i+=8)
        tile[ty+i][tx] = Wl[(size_t)(k0+ty+i)*H2 + n0+tx];
    __syncthreads();
    #pragma unroll
    for (int i=0;i<32;i+=8)
        Wtl[(size_t)(n0+ty+i)*H + k0+tx] = __float2bfloat16(tile[tx][ty+i]);
}

// ---------------- bf16 MFMA GEMM + bias + GLU fused ----------------
// A (M,K) bf16; Wt (2048,K) bf16 for one layer. Block: 128 m x 64 col-pairs.
// Bs rows: [0:32)=za(wc0) [32:64)=zb(wc0) [64:96)=za(wc1) [96:128)=zb(wc1)
// -> za/zb for same (m,c) land in same lane: acc[mi][ni] / acc[mi][ni+2].
__global__ __launch_bounds__(256) void k_gemm_glu_mfma(
        const __hip_bfloat16* __restrict__ Abf,
        const __hip_bfloat16* __restrict__ Wt,
        const float* __restrict__ bias2,         // (2048,)
        float* __restrict__ glu){                // (M,1024)
    __shared__ alignas(16) short As[128*32];   // 8 KB
    __shared__ alignas(16) short Bs[128*32];   // 8 KB
    const int K = 1024;
    int tid = threadIdx.x;
    int lane = tid & 63, wid = tid >> 6;
    int m0 = blockIdx.x * 128;
    int nb = blockIdx.y * 64;                  // col-pair base
    int g0 = tid, g1 = tid + 256;
    int r0 = g0 >> 2, r1 = g1 >> 2;
    int wtr0 = nb + ((r0>>6)<<5) + (r0&31) + ((r0>>5)&1)*1024;
    int wtr1 = nb + ((r1>>6)<<5) + (r1&31) + ((r1>>5)&1)*1024;
    const short* Ap = (const short*)Abf;
    const short* Bp = (const short*)Wt;
    const short* Ag0 = Ap + (size_t)(m0 + r0)*K + (g0&3)*8;
    const short* Ag1 = Ap + (size_t)(m0 + r1)*K + (g1&3)*8;
    const short* Bg0 = Bp + (size_t)wtr0*K + (g0&3)*8;
    const short* Bg1 = Bp + (size_t)wtr1*K + (g1&3)*8;
    char* AsB = (char*)As;
    char* BsB = (char*)Bs;
    int wr = wid >> 1, wc = wid & 1;
    int mo = wr*64, no = wc*64;
    f32x4 acc[4][4] = {};
    int arow = (lane & 15)*32 + (lane>>4)*8;
    for (int k0 = 0; k0 < K; k0 += 32){
        gload16(Ag0 + k0, AsB + wid*1024);
        gload16(Ag1 + k0, AsB + 4096 + wid*1024);
        gload16(Bg0 + k0, BsB + wid*1024);
        gload16(Bg1 + k0, BsB + 4096 + wid*1024);
        asm volatile("s_waitcnt vmcnt(0)" ::: "memory");
        __syncthreads();
        bf16x8 a[4], b[4];
        #pragma unroll
        for (int mi=0;mi<4;mi++)
            a[mi] = *(const bf16x8*)(As + (mo + mi*16)*32 + arow);
        #pragma unroll
        for (int ni=0;ni<4;ni++)
            b[ni] = *(const bf16x8*)(Bs + (no + ni*16)*32 + arow);
        #pragma unroll
        for (int mi=0;mi<4;mi++){
            #pragma unroll
            for (int ni=0;ni<4;ni++){
                acc[mi][ni] = __builtin_amdgcn_mfma_f32_16x16x32_bf16(a[mi], b[ni], acc[mi][ni], 0, 0, 0);
            }
        }
        __syncthreads();
    }
    // epilogue: GLU in-register; write (M,1024) f32
    int cbase = nb + wc*32 + (lane&15);
    #pragma unroll
    for (int ni=0;ni<2;ni++){
        int c = cbase + ni*16;
        float ba = bias2[c], bb = bias2[c+1024];
        #pragma unroll
        for (int mi=0;mi<4;mi++){
            #pragma unroll
            for (int r=0;r<4;r++){
                size_t m = m0 + mo + mi*16 + (lane>>4)*4 + r;
                float za = acc[mi][ni][r] + ba;
                float zb = acc[mi][ni+2][r] + bb;
                glu[m*H + c] = za * sigm_f(zb);
            }
        }
    }
}

// ---------------- LayerNorm over H per (b,t) row: out = LN(glu + res)*g + b ----------------
// out may alias res (row-private).
__global__ __launch_bounds__(256) void k_ln(const float* __restrict__ glu, const float* __restrict__ res,
        const float* __restrict__ gamma, const float* __restrict__ beta, float* __restrict__ outx){
    __shared__ float red[8];
    int row = blockIdx.x;
    int tid = threadIdx.x;
    float4 gv = *(const float4*)(glu + (size_t)row*H + tid*4);
    float4 rv = *(const float4*)(res + (size_t)row*H + tid*4);
    float x0=gv.x+rv.x, x1=gv.y+rv.y, x2=gv.z+rv.z, x3=gv.w+rv.w;
    float s = x0+x1+x2+x3;
    float q = x0*x0+x1*x1+x2*x2+x3*x3;
    #pragma unroll
    for (int m=32;m>=1;m>>=1){ s += __shfl_xor(s,m,64); q += __shfl_xor(q,m,64); }
    int wv = tid>>6;
    if ((tid&63)==0){ red[wv]=s; red[4+wv]=q; }
    __syncthreads();
    s = red[0]+red[1]+red[2]+red[3];
    q = red[4]+red[5]+red[6]+red[7];
    float m = s*(1.0f/H);
    float v = q*(1.0f/H) - m*m;
    float rstd = rsqrtf(v + 1e-5f);
    float4 gm = *(const float4*)(gamma + tid*4);
    float4 bt = *(const float4*)(beta + tid*4);
    float4 o;
    o.x = (x0-m)*rstd*gm.x + bt.x;
    o.y = (x1-m)*rstd*gm.y + bt.y;
    o.z = (x2-m)*rstd*gm.z + bt.z;
    o.w = (x3-m)*rstd*gm.w + bt.w;
    *(float4*)(outx + (size_t)row*H + tid*4) = o;
}

// ---------------- transpose (b,t,h) -> (b,h,t) f32 ----------------
__global__ __launch_bounds__(256) void k_transpose(const float* __restrict__ x, float* __restrict__ xT){
    __shared__ float tile[32][33];
    int t0 = blockIdx.x*32, h0 = blockIdx.y*32, b = blockIdx.z;
    int tx = threadIdx.x & 31, ty = threadIdx.x >> 5;
    #pragma unroll
    for (int i=0;i<32;i+=8)
        tile[ty+i][tx] = x[((size_t)(b*TLEN + t0+ty+i))*H + h0+tx];
    __syncthreads();
    #pragma unroll
    for (int i=0;i<32;i+=8)
        xT[((size_t)(b*H + h0+ty+i))*TLEN + t0+tx] = tile[tx][ty+i];
}

__global__ void k_ctx(const float* __restrict__ x, float* __restrict__ ctx){
    int i = blockIdx.x*256+threadIdx.x;
    int b = i>>10, h = i&(H-1);
    ctx[i] = x[((size_t)(b*TLEN + TLEN-1))*H + h];
}

// ---------------- decode: state update + y + gelu ----------------
__global__ __launch_bounds__(256) void k_dec_state(
        const float* __restrict__ dAr, const float* __restrict__ dAi,
        const float* __restrict__ dBr, const float* __restrict__ dBi,
        const float* __restrict__ Cre, const float* __restrict__ Cim,
        const float* __restrict__ Dv,
        float* __restrict__ sre, float* __restrict__ sim,
        const float* __restrict__ uin, int layer, int u_is_bits,
        float* __restrict__ ygel){
    int gtid = blockIdx.x*256 + threadIdx.x;
    int wid = gtid >> 6;
    int lane = gtid & 63;
    int b = wid >> 10, h = wid & (H-1);
    int pi = (layer*H + h)*NST + lane;
    size_t si = ((size_t)(layer*BSZ + b)*H + h)*NST + lane;
    float u = u_is_bits ? uin[b] : uin[b*H + h];
    float ar=dAr[pi], ai=dAi[pi], br=dBr[pi], bi=dBi[pi];
    float sr = sre[si], sI = sim[si];
    float nr = fmaf(ar,sr, fmaf(-ai,sI, br*u));
    float ni = fmaf(ai,sr, fmaf( ar,sI, bi*u));
    sre[si]=nr; sim[si]=ni;
    float c = Cre[pi]*nr - Cim[pi]*ni;
    #pragma unroll
    for (int m=1;m<64;m<<=1) c += __shfl_xor(c,m,64);
    if (lane==0){
        float y = 2.0f*c + Dv[layer*H+h]*u;
        ygel[b*H+h] = gelu_f(y);
    }
}

// ---------------- decode GEMM (32 x 2048 x 1024) + bias + GLU ----------------
__global__ __launch_bounds__(256) void k_dec_gemm(const float* __restrict__ ygel,
        const float* __restrict__ W, const float* __restrict__ bias2,
        float* __restrict__ glud){
    __shared__ float u_s[64][33];
    int tid = threadIdx.x;
    int p = blockIdx.x*8 + (tid>>5);
    int b = tid & 31;
    int sb = tid >> 3;
    int sk = (tid & 7) * 8;
    float aa=0.f, ab=0.f;
    for (int k0=0;k0<H;k0+=64){
        __syncthreads();
        float4 u0 = *(const float4*)(ygel + (size_t)sb*H + k0 + sk);
        float4 u1 = *(const float4*)(ygel + (size_t)sb*H + k0 + sk + 4);
        u_s[sk+0][sb]=u0.x; u_s[sk+1][sb]=u0.y; u_s[sk+2][sb]=u0.z; u_s[sk+3][sb]=u0.w;
        u_s[sk+4][sb]=u1.x; u_s[sk+5][sb]=u1.y; u_s[sk+6][sb]=u1.z; u_s[sk+7][sb]=u1.w;
        __syncthreads();
        #pragma unroll 8
        for (int k=0;k<64;k++){
            float wa = W[(size_t)(k0+k)*H2 + p];
            float wb = W[(size_t)(k0+k)*H2 + p + H];
            float u = u_s[k][b];
            aa = fmaf(u, wa, aa);
            ab = fmaf(u, wb, ab);
        }
    }
    float za = aa + bias2[p];
    float zb = ab + bias2[p+H];
    glud[b*H + p] = za * sigm_f(zb);
}

// ---------------- decode LN (+context+head+sigmoid for last layer) ----------------
__global__ __launch_bounds__(256) void k_dec_ln(
        const float* __restrict__ glud, const float* __restrict__ bits_in,
        const float* __restrict__ gamma, const float* __restrict__ beta,
        float* __restrict__ dec,
        const float* __restrict__ ctx, const float* __restrict__ headw,
        const float* __restrict__ headb,
        float* __restrict__ bits, float* __restrict__ out,
        int step, int last){
    __shared__ float red[8];
    int b = blockIdx.x, tid = threadIdx.x;
    float4 gv = *(const float4*)(glud + b*H + tid*4);
    float u0 = bits_in[b];
    float x0,x1,x2,x3;
    if (step==0){ x0=gv.x+u0; x1=gv.y+u0; x2=gv.z+u0; x3=gv.w+u0; }
    else        { x0=2.f*gv.x; x1=2.f*gv.y; x2=2.f*gv.z; x3=2.f*gv.w; }
    float s = x0+x1+x2+x3, q = x0*x0+x1*x1+x2*x2+x3*x3;
    #pragma unroll
    for (int m=32;m>=1;m>>=1){ s+=__shfl_xor(s,m,64); q+=__shfl_xor(q,m,64); }
    int wv = tid>>6;
    if ((tid&63)==0){ red[wv]=s; red[4+wv]=q; }
    __syncthreads();
    s = red[0]+red[1]+red[2]+red[3];
    q = red[4]+red[5]+red[6]+red[7];
    float m = s*(1.f/H), v = q*(1.f/H)-m*m, rstd = rsqrtf(v+1e-5f);
    float4 gm = *(const float4*)(gamma + tid*4);
    float4 bt = *(const float4*)(beta + tid*4);
    float d0 = (x0-m)*rstd*gm.x+bt.x;
    float d1 = (x1-m)*rstd*gm.y+bt.y;
    float d2 = (x2-m)*rstd*gm.z+bt.z;
    float d3 = (x3-m)*rstd*gm.w+bt.w;
    if (!last){
        float4 o; o.x=d0;o.y=d1;o.z=d2;o.w=d3;
        *(float4*)(dec + b*H + tid*4) = o;
    } else {
        float4 cv = *(const float4*)(ctx + b*H + tid*4);
        d0+=cv.x; d1+=cv.y; d2+=cv.z; d3+=cv.w;
        float4 hw = *(const float4*)(headw + tid*4);
        float hp = d0*hw.x + d1*hw.y + d2*hw.z + d3*hw.w;
        #pragma unroll
        for (int mm=32;mm>=1;mm>>=1) hp += __shfl_xor(hp,mm,64);
        __syncthreads();
        if ((tid&63)==0) red[wv]=hp;
        __syncthreads();
        if (tid==0){
            float hs = red[0]+red[1]+red[2]+red[3] + headb[0];
            float bit = sigm_f(hs);
            bits[b] = bit;
            out[b*NSTEPS + step] = bit;
        }
    }
}

extern "C" void kernel_launch(void* const* d_in, const int* in_sizes, int n_in,
                              void* d_out, int out_size, void* d_ws, size_t ws_size,
                              hipStream_t stream) {
    const float* in_seq = (const float*)d_in[0];
    const float* inw  = (const float*)d_in[2];
    const float* inb  = (const float*)d_in[3];
    const float* log_dt = (const float*)d_in[4];
    const float* Are = (const float*)d_in[5];
    const float* Aim = (const float*)d_in[6];
    const float* Bre = (const float*)d_in[7];
    const float* Bim = (const float*)d_in[8];
    const float* Cre = (const float*)d_in[9];
    const float* Cim = (const float*)d_in[10];
    const float* Dv  = (const float*)d_in[11];
    const float* outw = (const float*)d_in[12];
    const float* outb = (const float*)d_in[13];
    const float* lng = (const float*)d_in[14];
    const float* lnb = (const float*)d_in[15];
    const float* headw = (const float*)d_in[16];
    const float* headb = (const float*)d_in[17];
    float* out = (float*)d_out;

    float* ws = (float*)d_ws;
    size_t off = 0;
    auto alloc = [&](size_t n){ float* p = ws + off; off += n; return p; };
    float* dAr = alloc((size_t)LAYN*H*NST);
    float* dAi = alloc((size_t)LAYN*H*NST);
    float* dBr = alloc((size_t)LAYN*H*NST);
    float* dBi = alloc((size_t)LAYN*H*NST);
    float* Kbuf = alloc((size_t)LAYN*H*TLEN);
    float* bufA = alloc((size_t)BSZ*TLEN*H);                              // 67MB
    float* bufB = alloc((size_t)BSZ*TLEN*H);                              // 67MB
    __hip_bfloat16* gbf = (__hip_bfloat16*)alloc((size_t)BSZ*TLEN*H/2);   // 33.5MB
    float* ctx = alloc((size_t)BSZ*H);
    float* sre = alloc((size_t)LAYN*BSZ*H*NST);                           // 16.8MB
    float* sim = alloc((size_t)LAYN*BSZ*H*NST);                           // 16.8MB
    __hip_bfloat16* Abf = (__hip_bfloat16*)sre;  // alias: Abf dead before decode memsets
    __hip_bfloat16* Wt  = (__hip_bfloat16*)alloc((size_t)LAYN*H*H2/2);    // 8.4MB
    float* ygel = alloc((size_t)BSZ*H);
    float* glud = alloc((size_t)BSZ*H);
    float* dec  = alloc((size_t)BSZ*H);
    float* bits = alloc(64);
    // total ~216.5 MB (round-3's proven 241.7 MB was OK; round-4's 283.6 MB crashed)

    k_precompute<<<(LAYN*H*NST+255)/256, 256, 0, stream>>>(log_dt,Are,Aim,Bre,Bim,dAr,dAi,dBr,dBi);
    k_genK<<<LAYN*H, 64, 0, stream>>>(dAr,dAi,dBr,dBi,Cre,Cim,Kbuf);
    k_wtr<<<dim3(H2/32, H/32, LAYN), 256, 0, stream>>>(outw, Wt);
    k_inproj_x <<<(BSZ*TLEN*H)/256, 256, 0, stream>>>(in_seq, inw, inb, bufA);
    k_inproj_xT<<<(BSZ*TLEN*H)/256, 256, 0, stream>>>(in_seq, inw, inb, bufB);

    // ---- layer 0: res = bufA (b,t,h); xT = bufB (b,h,t)
    k_conv<<<dim3(TLEN/CTT, H), 256, 0, stream>>>(bufB, Kbuf, Dv, gbf, 0);
    k_trcast_bf<<<dim3(TLEN/32, H/32, BSZ), 256, 0, stream>>>(gbf, Abf);
    k_gemm_glu_mfma<<<dim3(BSZ*TLEN/128, H/64), 256, 0, stream>>>(Abf, Wt, outb, bufB);
    k_ln<<<BSZ*TLEN, 256, 0, stream>>>(bufB, bufA, lng, lnb, bufA);        // x1 -> bufA
    k_transpose<<<dim3(16,32,32), 256, 0, stream>>>(bufA, bufB);           // x1T -> bufB

    // ---- layer 1
    k_conv<<<dim3(TLEN/CTT, H), 256, 0, stream>>>(bufB, Kbuf, Dv, gbf, 1);
    k_trcast_bf<<<dim3(TLEN/32, H/32, BSZ), 256, 0, stream>>>(gbf, Abf);
    k_gemm_glu_mfma<<<dim3(BSZ*TLEN/128, H/64), 256, 0, stream>>>(Abf, Wt + (size_t)H*H2, outb + H2, bufB);
    k_ln<<<BSZ*TLEN, 256, 0, stream>>>(bufB, bufA, lng+H, lnb+H, bufA);    // x2 -> bufA

    k_ctx<<<(BSZ*H)/256, 256, 0, stream>>>(bufA, ctx);

    hipMemsetAsync(sre, 0, sizeof(float)*(size_t)LAYN*BSZ*H*NST, stream);
    hipMemsetAsync(sim, 0, sizeof(float)*(size_t)LAYN*BSZ*H*NST, stream);
    hipMemsetAsync(bits, 0, sizeof(float)*64, stream);

    for (int i=0;i<NSTEPS;i++){
        k_dec_state<<<(BSZ*H*64)/256, 256, 0, stream>>>(dAr,dAi,dBr,dBi,Cre,Cim,Dv,
                                                        sre,sim, bits, 0, 1, ygel);
        k_dec_gemm<<<128, 256, 0, stream>>>(ygel, outw, outb, glud);
        k_dec_ln<<<BSZ, 256, 0, stream>>>(glud, bits, lng, lnb, dec, ctx, headw, headb,
                                          bits, out, i, 0);
        k_dec_state<<<(BSZ*H*64)/256, 256, 0, stream>>>(dAr,dAi,dBr,dBi,Cre,Cim,Dv,
                                                        sre,sim, dec, 1, 0, ygel);
        k_dec_gemm<<<128, 256, 0, stream>>>(ygel, outw + (size_t)H*H2, outb + H2, glud);
        k_dec_ln<<<BSZ, 256, 0, stream>>>(glud, bits, lng+H, lnb+H, dec, ctx, headw, headb,
                                          bits, out, i, 1);
    }
}